// Round 9
// baseline (93.569 us; speedup 1.0000x reference)
//
#include <hip/hip_runtime.h>

#define B_   4
#define CIN  64
#define COUT 64
#define H_   128
#define W_   128
#define HW   (H_*W_)
#define KK   9
#define HALO 3
#define TI   4
#define TJ   16
#define ROWS_R (TI + 2*HALO)            // 10
#define COLS_R (TJ + 2*HALO)            // 22
#define RECS   (ROWS_R * COLS_R)        // 220
#define OFFB   (RECS * 128)             // 28160
#define SMEMB  (OFFB + 27 * TI * TJ * 4) // 35072
#define NBLK   1024                     // 4 b x 32 ti x 8 tj
#define FCAP   16384

typedef short bf16x8 __attribute__((ext_vector_type(8)));
typedef float f32x4  __attribute__((ext_vector_type(4)));
typedef float f32x2  __attribute__((ext_vector_type(2)));
typedef unsigned int u32;
typedef unsigned int u32x4 __attribute__((ext_vector_type(4)));

__device__ __forceinline__ unsigned short f2bf(float f) {
    unsigned int u = __float_as_uint(f);
    u = (u + 0x7FFFu + ((u >> 16) & 1u)) >> 16;
    return (unsigned short)u;
}
__device__ __forceinline__ float bf2f(unsigned short s) {
    return __uint_as_float(((unsigned int)s) << 16);
}

// ---- Kernel 1: x (B,CIN,H,W) f32 -> xt (B,H,W,CIN) bf16 ----
__global__ __launch_bounds__(256) void k_transpose(const float* __restrict__ x,
                                                   unsigned short* __restrict__ xt) {
    __shared__ float lds[64 * 129];
    int bi = blockIdx.x;
    int b = bi >> 7, i = bi & 127;
    int tid = threadIdx.x;
#pragma unroll
    for (int cc = 0; cc < 32; ++cc) {
        int c = cc * 2 + (tid >> 7);
        int w = tid & 127;
        lds[c * 129 + w] = x[((b * CIN + c) * H_ + i) * W_ + w];
    }
    __syncthreads();
#pragma unroll
    for (int q = 0; q < 32; ++q) {
        int c = tid & 63;
        int w = q * 4 + (tid >> 6);
        xt[((b * H_ + i) * W_ + w) * CIN + c] = f2bf(lds[c * 129 + w]);
    }
}

// ---- Kernel 2: weight -> MFMA B-fragment order (bf16) ----
__global__ __launch_bounds__(256) void k_weight(const float* __restrict__ w,
                                                unsigned short* __restrict__ wtf) {
    int t = blockIdx.x * 256 + threadIdx.x;
    if (t >= 18 * 4 * 64 * 8) return;
    int j    = t & 7;
    int lane = (t >> 3) & 63;
    int nt   = (t >> 9) & 3;
    int s    = t >> 11;
    int kg   = s * 32 + ((lane >> 4) << 3) + j;
    int n    = nt * 16 + (lane & 15);
    int kpos = kg >> 6, c = kg & 63;
    wtf[t] = f2bf(w[(n * CIN + c) * 9 + kpos]);
}

// ---- Kernel 2b: weight -> wfix[kp][c][cout] f32 (for fixup matvec) ----
__global__ __launch_bounds__(256) void k_wfix(const float* __restrict__ w,
                                              float* __restrict__ wfix) {
    int t = blockIdx.x * 256 + threadIdx.x;   // 36864 total
    int kp = t >> 12, c = (t >> 6) & 63, cout = t & 63;
    wfix[t] = w[(cout * CIN + c) * 9 + kp];
}

// ---- Main: 4x16 tile, 8 waves = 4 px-rows x 2 K-halves, branch-free ----
__global__ __launch_bounds__(512, 8) void k_main(
    const unsigned short* __restrict__ xt,
    const float* __restrict__ offset,
    const float* __restrict__ mask,
    const unsigned short* __restrict__ wtf,
    const float* __restrict__ bias,
    float* __restrict__ out,
    unsigned* __restrict__ counter,
    unsigned* __restrict__ flags) {
    __shared__ __align__(16) unsigned char smem[SMEMB];   // 34.25 KB

    const int tid  = threadIdx.x;
    const int lane = tid & 63;
    const int wv   = tid >> 6;          // 0..7
    const int wvl  = wv & 3;            // px row within tile
    const int half = wv >> 2;           // K-half
    // XCD swizzle (1024 % 8 == 0)
    const int T  = ((blockIdx.x & 7) << 7) + (blockIdx.x >> 3);
    const int b  = T >> 8;
    const int i0 = ((T >> 3) & 31) * TI;
    const int j0 = (T & 7) * TJ;
    const char* xb = (const char*)xt + (size_t)b * HW * 128;

    // -------- stage 10x22 record region, chunk-rotation swizzle --------
    {
        const int iA = i0 - HALO, jA = j0 - HALO;
#pragma unroll
        for (int k = 0; k < 4; ++k) {
            int idx = k * 512 + tid;          // 1760 chunks
            if (idx < RECS * 8) {
                int rec = idx >> 3, c = idx & 7;
                int rr = rec / COLS_R, cc = rec - rr * COLS_R;
                int gr = min(max(iA + rr, 0), H_ - 1);
                int gc = min(max(jA + cc, 0), W_ - 1);
                u32x4 v = *(const u32x4*)(xb + (((gr << 7) + gc) << 7) + (c << 4));
                *(u32x4*)(smem + (rec << 7) + (((c + rec) & 7) << 4)) = v;
            }
        }
    }
    // -------- stage offset+mask planes [27][4][16] f32 --------
    {
        const float* op = offset + (size_t)b * 18 * HW;
        const float* mp = mask   + (size_t)b * 9  * HW;
        if (tid < 432) {
            int q = tid >> 4, rem = tid & 15;
            int row = rem >> 2, c4 = (rem & 3) << 2;
            const float* src = (q < 18 ? op + q * HW : mp + (q - 18) * HW)
                               + (i0 + row) * W_ + j0 + c4;
            *(f32x4*)(smem + OFFB + tid * 16) = *(const f32x4*)src;
        }
    }
    __syncthreads();

    const int p  = lane & 15;            // px col
    const int g  = lane >> 4;            // channel group
    const int ir = i0 + wvl;
    const int jc = j0 + p;
    const float* offl = (const float*)(smem + OFFB) + wvl * 16 + p;
    const bf16x8* wp = (const bf16x8*)wtf;
    f32x4 acc0 = {0,0,0,0}, acc1 = {0,0,0,0}, acc2 = {0,0,0,0}, acc3 = {0,0,0,0};
    int omask = 0;

#define KP_BODY(KP, H0, H1, FLAG) do { \
    float oi  = offl[(2*(KP)) * 64]; \
    float oj  = offl[(2*(KP)+1) * 64]; \
    float msk = offl[(18+(KP)) * 64]; \
    float ci = oi + (float)(ir + (KP)/3 - 1); \
    float cj = oj + (float)(jc + (KP)%3 - 1); \
    float fli = floorf(ci), flj = floorf(cj); \
    float fi = ci - fli, fj = cj - flj; \
    int li = (int)fli, lj = (int)flj; \
    int rli = li - (i0 - HALO), rlj = lj - (j0 - HALO); \
    bool inr = ((unsigned)rli <= (unsigned)(ROWS_R-2)) && \
               ((unsigned)rlj <= (unsigned)(COLS_R-2)); \
    if (FLAG) omask |= (inr ? 0 : 1) << (KP); \
    msk = inr ? msk : 0.f; \
    float vy0 = (li   >= 0 && li   < H_) ? 1.f : 0.f; \
    float vy1 = (li+1 >= 0 && li+1 < H_) ? 1.f : 0.f; \
    float vx0 = (lj   >= 0 && lj   < W_) ? 1.f : 0.f; \
    float vx1 = (lj+1 >= 0 && lj+1 < W_) ? 1.f : 0.f; \
    float gi = fi * msk, gj = fj * msk; \
    float w11 = gi * fj; \
    float w4x = (msk - gi - gj + w11) * vy0 * vx0; \
    float w4y = (gj - w11) * vy0 * vx1; \
    float w4z = (gi - w11) * vy1 * vx0; \
    float w4w = w11 * vy1 * vx1; \
    int rli_c = min(max(rli, 0), ROWS_R-2), rlj_c = min(max(rlj, 0), COLS_R-2); \
    int r00 = rli_c * COLS_R + rlj_c; \
    int r01 = r00 + 1, r10 = r00 + COLS_R, r11 = r00 + COLS_R + 1; \
    f32x2 wx = {w4x, w4x}, wy = {w4y, w4y}, wz = {w4z, w4z}, ww = {w4w, w4w}; \
    _Pragma("unroll") \
    for (int h = (H0); h < (H1); ++h) { \
        int ch = h * 4 + g; \
        u32x4 q00 = *(const u32x4*)(smem + (r00 << 7) + (((ch + r00) & 7) << 4)); \
        u32x4 q01 = *(const u32x4*)(smem + (r01 << 7) + (((ch + r01) & 7) << 4)); \
        u32x4 q10 = *(const u32x4*)(smem + (r10 << 7) + (((ch + r10) & 7) << 4)); \
        u32x4 q11 = *(const u32x4*)(smem + (r11 << 7) + (((ch + r11) & 7) << 4)); \
        u32x4 po; \
        _Pragma("unroll") \
        for (int q = 0; q < 4; ++q) { \
            f32x2 c00 = {__uint_as_float(q00[q] << 16), __uint_as_float(q00[q] & 0xFFFF0000u)}; \
            f32x2 c01 = {__uint_as_float(q01[q] << 16), __uint_as_float(q01[q] & 0xFFFF0000u)}; \
            f32x2 c10 = {__uint_as_float(q10[q] << 16), __uint_as_float(q10[q] & 0xFFFF0000u)}; \
            f32x2 c11 = {__uint_as_float(q11[q] << 16), __uint_as_float(q11[q] & 0xFFFF0000u)}; \
            f32x2 r = wx * c00 + wy * c01 + wz * c10 + ww * c11; \
            po[q] = __builtin_amdgcn_perm(__float_as_uint(r.y) + 0x8000u, \
                                          __float_as_uint(r.x) + 0x8000u, 0x07060302u); \
        } \
        bf16x8 af; *(u32x4*)&af = po; \
        int s = (KP) * 2 + h; \
        acc0 = __builtin_amdgcn_mfma_f32_16x16x32_bf16(af, wp[(s*4+0)*64 + lane], acc0, 0, 0, 0); \
        acc1 = __builtin_amdgcn_mfma_f32_16x16x32_bf16(af, wp[(s*4+1)*64 + lane], acc1, 0, 0, 0); \
        acc2 = __builtin_amdgcn_mfma_f32_16x16x32_bf16(af, wp[(s*4+2)*64 + lane], acc2, 0, 0, 0); \
        acc3 = __builtin_amdgcn_mfma_f32_16x16x32_bf16(af, wp[(s*4+3)*64 + lane], acc3, 0, 0, 0); \
    } } while (0)

    if (!half) {
        KP_BODY(0, 0, 2, 1); KP_BODY(1, 0, 2, 1); KP_BODY(2, 0, 2, 1);
        KP_BODY(3, 0, 2, 1); KP_BODY(8, 0, 1, 1);        // kp8 h0; lo flags kp8
    } else {
        KP_BODY(4, 0, 2, 1); KP_BODY(5, 0, 2, 1); KP_BODY(6, 0, 2, 1);
        KP_BODY(7, 0, 2, 1); KP_BODY(8, 1, 2, 0);        // kp8 h1; no flag (dedup)
    }

    // -------- flush outlier flags (rare) --------
    if (g == 0 && omask) {
        unsigned pxg = ((unsigned)b << 14) | ((unsigned)ir << 7) | (unsigned)jc;
        while (omask) {
            int kp = __ffs(omask) - 1; omask &= omask - 1;
            unsigned idx = atomicAdd(counter, 1u);
            if (idx < FCAP) flags[idx] = (pxg << 4) | (unsigned)kp;
        }
    }

    // -------- epilogue: K-reduce via LDS, bias, coalesced write --------
    __syncthreads();
    f32x4* dump = (f32x4*)smem;                  // [nt][4 rows][64 lanes]
    if (half) {
        dump[(0*4 + wvl)*64 + lane] = acc0;
        dump[(1*4 + wvl)*64 + lane] = acc1;
        dump[(2*4 + wvl)*64 + lane] = acc2;
        dump[(3*4 + wvl)*64 + lane] = acc3;
    }
    __syncthreads();
    if (!half) {
        acc0 += dump[(0*4 + wvl)*64 + lane];
        acc1 += dump[(1*4 + wvl)*64 + lane];
        acc2 += dump[(2*4 + wvl)*64 + lane];
        acc3 += dump[(3*4 + wvl)*64 + lane];
        float bs0 = bias[p], bs1 = bias[16 + p], bs2 = bias[32 + p], bs3 = bias[48 + p];
#pragma unroll
        for (int r = 0; r < 4; ++r) { acc0[r] += bs0; acc1[r] += bs1; acc2[r] += bs2; acc3[r] += bs3; }
    }
    __syncthreads();
    float* cst = (float*)smem;                   // [64 cout][68 px]
    if (!half) {
        const int pm = wvl * 16 + (g << 2);      // px-local base
        *(f32x4*)&cst[(p)      * 68 + pm] = acc0;
        *(f32x4*)&cst[(16 + p) * 68 + pm] = acc1;
        *(f32x4*)&cst[(32 + p) * 68 + pm] = acc2;
        *(f32x4*)&cst[(48 + p) * 68 + pm] = acc3;
    }
    __syncthreads();
    const size_t obase = (size_t)b * (COUT * HW) + i0 * W_ + j0;
#pragma unroll
    for (int k = 0; k < 2; ++k) {
        int idx = k * 512 + tid;                 // 1024 f32x4 chunks
        int cout = idx >> 4, chunk = idx & 15;
        int row = chunk >> 2, cq = (chunk & 3) << 2;
        f32x4 vv = *(const f32x4*)&cst[cout * 68 + chunk * 4];
        __builtin_nontemporal_store(vv,
            (f32x4*)&out[obase + (size_t)cout * HW + row * W_ + cq]);
    }
}

// ---- Fixup: re-gather flagged (px,kp) samples, atomicAdd W·v to out ----
__global__ __launch_bounds__(256) void k_fixup(
    const unsigned short* __restrict__ xt,
    const float* __restrict__ offset,
    const float* __restrict__ mask,
    const float* __restrict__ wfix,
    const unsigned* __restrict__ counter,
    const unsigned* __restrict__ flags,
    float* __restrict__ out) {
    const int wid  = (blockIdx.x * 256 + threadIdx.x) >> 6;   // 1024 waves
    const int lane = threadIdx.x & 63;
    unsigned n = *counter; if (n > FCAP) n = FCAP;
    for (unsigned e = wid; e < n; e += 1024) {
        unsigned code = flags[e];
        int kp = code & 15;
        unsigned px = code >> 4;
        int b = px >> 14, ii = (px >> 7) & 127, jj = px & 127;
        int hw = ii * W_ + jj;
        float oi  = offset[((size_t)b * 18 + 2 * kp) * HW + hw];
        float oj  = offset[((size_t)b * 18 + 2 * kp + 1) * HW + hw];
        float msk = mask[((size_t)b * 9 + kp) * HW + hw];
        int r3 = kp / 3;
        float ci = oi + (float)(ii + r3 - 1);
        float cj = oj + (float)(jj + (kp - r3 * 3) - 1);
        float fli = floorf(ci), flj = floorf(cj);
        float fi = ci - fli, fj = cj - flj;
        int li = (int)fli, lj = (int)flj;
        float vy0 = (li   >= 0 && li   < H_) ? 1.f : 0.f;
        float vy1 = (li+1 >= 0 && li+1 < H_) ? 1.f : 0.f;
        float vx0 = (lj   >= 0 && lj   < W_) ? 1.f : 0.f;
        float vx1 = (lj+1 >= 0 && lj+1 < W_) ? 1.f : 0.f;
        int y0 = min(max(li,   0), H_ - 1), y1 = min(max(li+1, 0), H_ - 1);
        int x0 = min(max(lj,   0), W_ - 1), x1 = min(max(lj+1, 0), W_ - 1);
        float gi = fi * msk, gj = fj * msk;
        float w11 = gi * fj;
        float w00 = (msk - gi - gj + w11) * vy0 * vx0;
        float w01 = (gj - w11) * vy0 * vx1;
        float w10 = (gi - w11) * vy1 * vx0;
        float w11w = w11 * vy1 * vx1;
        const unsigned short* xr = xt + (size_t)b * HW * CIN;
        float v00 = bf2f(xr[((y0 << 7) + x0) * CIN + lane]);
        float v01 = bf2f(xr[((y0 << 7) + x1) * CIN + lane]);
        float v10 = bf2f(xr[((y1 << 7) + x0) * CIN + lane]);
        float v11 = bf2f(xr[((y1 << 7) + x1) * CIN + lane]);
        float v = w00 * v00 + w01 * v01 + w10 * v10 + w11w * v11;
        float acc = 0.f;
        const float* wk = wfix + (size_t)kp * 64 * 64 + lane;
#pragma unroll 8
        for (int c = 0; c < 64; ++c)
            acc = fmaf(__shfl(v, c), wk[c * 64], acc);
        atomicAdd(&out[((size_t)(b * COUT) + lane) * HW + hw], acc);
    }
}

extern "C" void kernel_launch(void* const* d_in, const int* in_sizes, int n_in,
                              void* d_out, int out_size, void* d_ws, size_t ws_size,
                              hipStream_t stream) {
    const float* x      = (const float*)d_in[0];
    const float* offset = (const float*)d_in[1];
    const float* mask   = (const float*)d_in[2];
    const float* weight = (const float*)d_in[3];
    const float* bias   = (const float*)d_in[4];
    float* out = (float*)d_out;
    char* ws = (char*)d_ws;
    unsigned short* xt  = (unsigned short*)ws;                        // 8 MB
    unsigned short* wtf = (unsigned short*)(ws + 8388608);            // 72 KB
    float* wfix         = (float*)(ws + 8388608 + 73728);             // 144 KB
    unsigned* counter   = (unsigned*)(ws + 8388608 + 73728 + 147456);
    unsigned* flags     = counter + 32;                               // 64 KB

    hipMemsetAsync(counter, 0, 4, stream);
    k_transpose<<<B_ * H_, 256, 0, stream>>>(x, xt);
    k_weight<<<144, 256, 0, stream>>>(weight, wtf);
    k_wfix<<<144, 256, 0, stream>>>(weight, wfix);
    k_main<<<NBLK, 512, 0, stream>>>(xt, offset, mask, wtf, bias, out, counter, flags);
    k_fixup<<<256, 256, 0, stream>>>(xt, offset, mask, wfix, counter, flags, out);
}

// Round 10
// 74.575 us; speedup vs baseline: 1.2547x; 1.2547x over previous
//
#include <hip/hip_runtime.h>

#define B_   4
#define CIN  64
#define COUT 64
#define H_   128
#define W_   128
#define HW   (H_*W_)
#define KK   9
#define HALO 3
#define TI   4
#define TJ   16
#define ROWS_R (TI + 2*HALO)            // 10
#define COLS_R (TJ + 2*HALO)            // 22
#define RECS   (ROWS_R * COLS_R)        // 220
#define OFFB   (RECS * 128)             // 28160
#define SMEMB  (OFFB + 27 * TI * TJ * 4) // 35072
#define NBLK   1024                     // 4 b x 32 ti x 8 tj
#define FCAP   16384

typedef short bf16x8 __attribute__((ext_vector_type(8)));
typedef float f32x4  __attribute__((ext_vector_type(4)));
typedef float f32x2  __attribute__((ext_vector_type(2)));
typedef unsigned int u32;
typedef unsigned int u32x4 __attribute__((ext_vector_type(4)));

__device__ __forceinline__ unsigned short f2bf(float f) {
    unsigned int u = __float_as_uint(f);
    u = (u + 0x7FFFu + ((u >> 16) & 1u)) >> 16;
    return (unsigned short)u;
}
__device__ __forceinline__ float bf2f(unsigned short s) {
    return __uint_as_float(((unsigned int)s) << 16);
}

// ---- Kernel 1: x (B,CIN,H,W) f32 -> xt (B,H,W,CIN) bf16 ----
__global__ __launch_bounds__(256) void k_transpose(const float* __restrict__ x,
                                                   unsigned short* __restrict__ xt) {
    __shared__ float lds[64 * 129];
    int bi = blockIdx.x;
    int b = bi >> 7, i = bi & 127;
    int tid = threadIdx.x;
#pragma unroll
    for (int cc = 0; cc < 32; ++cc) {
        int c = cc * 2 + (tid >> 7);
        int w = tid & 127;
        lds[c * 129 + w] = x[((b * CIN + c) * H_ + i) * W_ + w];
    }
    __syncthreads();
#pragma unroll
    for (int q = 0; q < 32; ++q) {
        int c = tid & 63;
        int w = q * 4 + (tid >> 6);
        xt[((b * H_ + i) * W_ + w) * CIN + c] = f2bf(lds[c * 129 + w]);
    }
}

// ---- Kernel 2: weight -> MFMA B-fragment order (bf16) ----
__global__ __launch_bounds__(256) void k_weight(const float* __restrict__ w,
                                                unsigned short* __restrict__ wtf) {
    int t = blockIdx.x * 256 + threadIdx.x;
    if (t >= 18 * 4 * 64 * 8) return;
    int j    = t & 7;
    int lane = (t >> 3) & 63;
    int nt   = (t >> 9) & 3;
    int s    = t >> 11;
    int kg   = s * 32 + ((lane >> 4) << 3) + j;
    int n    = nt * 16 + (lane & 15);
    int kpos = kg >> 6, c = kg & 63;
    wtf[t] = f2bf(w[(n * CIN + c) * 9 + kpos]);
}

// ---- Kernel 2b: weight -> wfix[kp][c][cout] f32 (for fixup matvec) ----
__global__ __launch_bounds__(256) void k_wfix(const float* __restrict__ w,
                                              float* __restrict__ wfix) {
    int t = blockIdx.x * 256 + threadIdx.x;   // 36864 total
    int kp = t >> 12, c = (t >> 6) & 63, cout = t & 63;
    wfix[t] = w[(cout * CIN + c) * 9 + kp];
}

// ---- Main: 4x16 tile, 8 waves = 4 px-rows x 2 K-halves, branch-free ----
__global__ __launch_bounds__(512, 6) void k_main(
    const unsigned short* __restrict__ xt,
    const float* __restrict__ offset,
    const float* __restrict__ mask,
    const unsigned short* __restrict__ wtf,
    const float* __restrict__ bias,
    float* __restrict__ out,
    unsigned* __restrict__ counter,
    unsigned* __restrict__ flags) {
    __shared__ __align__(16) unsigned char smem[SMEMB];   // 34.25 KB

    const int tid  = threadIdx.x;
    const int lane = tid & 63;
    const int wv   = tid >> 6;          // 0..7
    const int wvl  = wv & 3;            // px row within tile
    const int half = wv >> 2;           // K-half
    // XCD swizzle (1024 % 8 == 0)
    const int T  = ((blockIdx.x & 7) << 7) + (blockIdx.x >> 3);
    const int b  = T >> 8;
    const int i0 = ((T >> 3) & 31) * TI;
    const int j0 = (T & 7) * TJ;
    const char* xb = (const char*)xt + (size_t)b * HW * 128;

    // -------- stage 10x22 record region, chunk-rotation swizzle --------
    {
        const int iA = i0 - HALO, jA = j0 - HALO;
#pragma unroll
        for (int k = 0; k < 4; ++k) {
            int idx = k * 512 + tid;          // 1760 chunks
            if (idx < RECS * 8) {
                int rec = idx >> 3, c = idx & 7;
                int rr = rec / COLS_R, cc = rec - rr * COLS_R;
                int gr = min(max(iA + rr, 0), H_ - 1);
                int gc = min(max(jA + cc, 0), W_ - 1);
                u32x4 v = *(const u32x4*)(xb + (((gr << 7) + gc) << 7) + (c << 4));
                *(u32x4*)(smem + (rec << 7) + (((c + rec) & 7) << 4)) = v;
            }
        }
    }
    // -------- stage offset+mask planes [27][4][16] f32 --------
    {
        const float* op = offset + (size_t)b * 18 * HW;
        const float* mp = mask   + (size_t)b * 9  * HW;
        if (tid < 432) {
            int q = tid >> 4, rem = tid & 15;
            int row = rem >> 2, c4 = (rem & 3) << 2;
            const float* src = (q < 18 ? op + q * HW : mp + (q - 18) * HW)
                               + (i0 + row) * W_ + j0 + c4;
            *(f32x4*)(smem + OFFB + tid * 16) = *(const f32x4*)src;
        }
    }
    __syncthreads();

    const int p  = lane & 15;            // px col
    const int g  = lane >> 4;            // channel group
    const int ir = i0 + wvl;
    const int jc = j0 + p;
    const float* offl = (const float*)(smem + OFFB) + wvl * 16 + p;
    const bf16x8* wp = (const bf16x8*)wtf;
    f32x4 acc0 = {0,0,0,0}, acc1 = {0,0,0,0}, acc2 = {0,0,0,0}, acc3 = {0,0,0,0};
    int omask = 0;

#define KP_BODY(KP, H0, H1, FLAG) do { \
    float oi  = offl[(2*(KP)) * 64]; \
    float oj  = offl[(2*(KP)+1) * 64]; \
    float msk = offl[(18+(KP)) * 64]; \
    float ci = oi + (float)(ir + (KP)/3 - 1); \
    float cj = oj + (float)(jc + (KP)%3 - 1); \
    float fli = floorf(ci), flj = floorf(cj); \
    float fi = ci - fli, fj = cj - flj; \
    int li = (int)fli, lj = (int)flj; \
    int rli = li - (i0 - HALO), rlj = lj - (j0 - HALO); \
    bool inr = ((unsigned)rli <= (unsigned)(ROWS_R-2)) && \
               ((unsigned)rlj <= (unsigned)(COLS_R-2)); \
    if (FLAG) omask |= (inr ? 0 : 1) << (KP); \
    msk = inr ? msk : 0.f; \
    float vy0 = (li   >= 0 && li   < H_) ? 1.f : 0.f; \
    float vy1 = (li+1 >= 0 && li+1 < H_) ? 1.f : 0.f; \
    float vx0 = (lj   >= 0 && lj   < W_) ? 1.f : 0.f; \
    float vx1 = (lj+1 >= 0 && lj+1 < W_) ? 1.f : 0.f; \
    float gi = fi * msk, gj = fj * msk; \
    float w11 = gi * fj; \
    float w4x = (msk - gi - gj + w11) * vy0 * vx0; \
    float w4y = (gj - w11) * vy0 * vx1; \
    float w4z = (gi - w11) * vy1 * vx0; \
    float w4w = w11 * vy1 * vx1; \
    int rli_c = min(max(rli, 0), ROWS_R-2), rlj_c = min(max(rlj, 0), COLS_R-2); \
    int r00 = rli_c * COLS_R + rlj_c; \
    int r01 = r00 + 1, r10 = r00 + COLS_R, r11 = r00 + COLS_R + 1; \
    f32x2 wx = {w4x, w4x}, wy = {w4y, w4y}, wz = {w4z, w4z}, ww = {w4w, w4w}; \
    _Pragma("unroll") \
    for (int h = (H0); h < (H1); ++h) { \
        int ch = h * 4 + g; \
        u32x4 q00 = *(const u32x4*)(smem + (r00 << 7) + (((ch + r00) & 7) << 4)); \
        u32x4 q01 = *(const u32x4*)(smem + (r01 << 7) + (((ch + r01) & 7) << 4)); \
        u32x4 q10 = *(const u32x4*)(smem + (r10 << 7) + (((ch + r10) & 7) << 4)); \
        u32x4 q11 = *(const u32x4*)(smem + (r11 << 7) + (((ch + r11) & 7) << 4)); \
        u32x4 po; \
        _Pragma("unroll") \
        for (int q = 0; q < 4; ++q) { \
            f32x2 c00 = {__uint_as_float(q00[q] << 16), __uint_as_float(q00[q] & 0xFFFF0000u)}; \
            f32x2 c01 = {__uint_as_float(q01[q] << 16), __uint_as_float(q01[q] & 0xFFFF0000u)}; \
            f32x2 c10 = {__uint_as_float(q10[q] << 16), __uint_as_float(q10[q] & 0xFFFF0000u)}; \
            f32x2 c11 = {__uint_as_float(q11[q] << 16), __uint_as_float(q11[q] & 0xFFFF0000u)}; \
            f32x2 r = wx * c00 + wy * c01 + wz * c10 + ww * c11; \
            po[q] = __builtin_amdgcn_perm(__float_as_uint(r.y) + 0x8000u, \
                                          __float_as_uint(r.x) + 0x8000u, 0x07060302u); \
        } \
        bf16x8 af; *(u32x4*)&af = po; \
        int s = (KP) * 2 + h; \
        acc0 = __builtin_amdgcn_mfma_f32_16x16x32_bf16(af, wp[(s*4+0)*64 + lane], acc0, 0, 0, 0); \
        acc1 = __builtin_amdgcn_mfma_f32_16x16x32_bf16(af, wp[(s*4+1)*64 + lane], acc1, 0, 0, 0); \
        acc2 = __builtin_amdgcn_mfma_f32_16x16x32_bf16(af, wp[(s*4+2)*64 + lane], acc2, 0, 0, 0); \
        acc3 = __builtin_amdgcn_mfma_f32_16x16x32_bf16(af, wp[(s*4+3)*64 + lane], acc3, 0, 0, 0); \
    } } while (0)

    if (!half) {
        KP_BODY(0, 0, 2, 1); KP_BODY(1, 0, 2, 1); KP_BODY(2, 0, 2, 1);
        KP_BODY(3, 0, 2, 1); KP_BODY(8, 0, 1, 1);        // kp8 h0; lo flags kp8
    } else {
        KP_BODY(4, 0, 2, 1); KP_BODY(5, 0, 2, 1); KP_BODY(6, 0, 2, 1);
        KP_BODY(7, 0, 2, 1); KP_BODY(8, 1, 2, 0);        // kp8 h1; no flag (dedup)
    }

    // -------- flush outlier flags (rare) --------
    if (g == 0 && omask) {
        unsigned pxg = ((unsigned)b << 14) | ((unsigned)ir << 7) | (unsigned)jc;
        while (omask) {
            int kp = __ffs(omask) - 1; omask &= omask - 1;
            unsigned idx = atomicAdd(counter, 1u);
            if (idx < FCAP) flags[idx] = (pxg << 4) | (unsigned)kp;
        }
    }

    // -------- epilogue: K-reduce via LDS, bias, coalesced write --------
    __syncthreads();
    f32x4* dump = (f32x4*)smem;                  // [nt][4 rows][64 lanes]
    if (half) {
        dump[(0*4 + wvl)*64 + lane] = acc0;
        dump[(1*4 + wvl)*64 + lane] = acc1;
        dump[(2*4 + wvl)*64 + lane] = acc2;
        dump[(3*4 + wvl)*64 + lane] = acc3;
    }
    __syncthreads();
    if (!half) {
        acc0 += dump[(0*4 + wvl)*64 + lane];
        acc1 += dump[(1*4 + wvl)*64 + lane];
        acc2 += dump[(2*4 + wvl)*64 + lane];
        acc3 += dump[(3*4 + wvl)*64 + lane];
        float bs0 = bias[p], bs1 = bias[16 + p], bs2 = bias[32 + p], bs3 = bias[48 + p];
#pragma unroll
        for (int r = 0; r < 4; ++r) { acc0[r] += bs0; acc1[r] += bs1; acc2[r] += bs2; acc3[r] += bs3; }
    }
    __syncthreads();
    float* cst = (float*)smem;                   // [64 cout][68 px]
    if (!half) {
        const int pm = wvl * 16 + (g << 2);      // px-local base
        *(f32x4*)&cst[(p)      * 68 + pm] = acc0;
        *(f32x4*)&cst[(16 + p) * 68 + pm] = acc1;
        *(f32x4*)&cst[(32 + p) * 68 + pm] = acc2;
        *(f32x4*)&cst[(48 + p) * 68 + pm] = acc3;
    }
    __syncthreads();
    const size_t obase = (size_t)b * (COUT * HW) + i0 * W_ + j0;
#pragma unroll
    for (int k = 0; k < 2; ++k) {
        int idx = k * 512 + tid;                 // 1024 f32x4 chunks
        int cout = idx >> 4, chunk = idx & 15;
        int row = chunk >> 2, cq = (chunk & 3) << 2;
        f32x4 vv = *(const f32x4*)&cst[cout * 68 + chunk * 4];
        __builtin_nontemporal_store(vv,
            (f32x4*)&out[obase + (size_t)cout * HW + row * W_ + cq]);
    }
}

// ---- Fixup: re-gather flagged (px,kp) samples, atomicAdd W·v to out ----
__global__ __launch_bounds__(256) void k_fixup(
    const unsigned short* __restrict__ xt,
    const float* __restrict__ offset,
    const float* __restrict__ mask,
    const float* __restrict__ wfix,
    const unsigned* __restrict__ counter,
    const unsigned* __restrict__ flags,
    float* __restrict__ out) {
    const int wid  = (blockIdx.x * 256 + threadIdx.x) >> 6;   // 1024 waves
    const int lane = threadIdx.x & 63;
    unsigned n = *counter; if (n > FCAP) n = FCAP;
    for (unsigned e = wid; e < n; e += 1024) {
        unsigned code = flags[e];
        int kp = code & 15;
        unsigned px = code >> 4;
        int b = px >> 14, ii = (px >> 7) & 127, jj = px & 127;
        int hw = ii * W_ + jj;
        float oi  = offset[((size_t)b * 18 + 2 * kp) * HW + hw];
        float oj  = offset[((size_t)b * 18 + 2 * kp + 1) * HW + hw];
        float msk = mask[((size_t)b * 9 + kp) * HW + hw];
        int r3 = kp / 3;
        float ci = oi + (float)(ii + r3 - 1);
        float cj = oj + (float)(jj + (kp - r3 * 3) - 1);
        float fli = floorf(ci), flj = floorf(cj);
        float fi = ci - fli, fj = cj - flj;
        int li = (int)fli, lj = (int)flj;
        float vy0 = (li   >= 0 && li   < H_) ? 1.f : 0.f;
        float vy1 = (li+1 >= 0 && li+1 < H_) ? 1.f : 0.f;
        float vx0 = (lj   >= 0 && lj   < W_) ? 1.f : 0.f;
        float vx1 = (lj+1 >= 0 && lj+1 < W_) ? 1.f : 0.f;
        int y0 = min(max(li,   0), H_ - 1), y1 = min(max(li+1, 0), H_ - 1);
        int x0 = min(max(lj,   0), W_ - 1), x1 = min(max(lj+1, 0), W_ - 1);
        float gi = fi * msk, gj = fj * msk;
        float w11 = gi * fj;
        float w00 = (msk - gi - gj + w11) * vy0 * vx0;
        float w01 = (gj - w11) * vy0 * vx1;
        float w10 = (gi - w11) * vy1 * vx0;
        float w11w = w11 * vy1 * vx1;
        const unsigned short* xr = xt + (size_t)b * HW * CIN;
        float v00 = bf2f(xr[((y0 << 7) + x0) * CIN + lane]);
        float v01 = bf2f(xr[((y0 << 7) + x1) * CIN + lane]);
        float v10 = bf2f(xr[((y1 << 7) + x0) * CIN + lane]);
        float v11 = bf2f(xr[((y1 << 7) + x1) * CIN + lane]);
        float v = w00 * v00 + w01 * v01 + w10 * v10 + w11w * v11;
        float acc = 0.f;
        const float* wk = wfix + (size_t)kp * 64 * 64 + lane;
#pragma unroll 8
        for (int c = 0; c < 64; ++c)
            acc = fmaf(__shfl(v, c), wk[c * 64], acc);
        atomicAdd(&out[((size_t)(b * COUT) + lane) * HW + hw], acc);
    }
}

extern "C" void kernel_launch(void* const* d_in, const int* in_sizes, int n_in,
                              void* d_out, int out_size, void* d_ws, size_t ws_size,
                              hipStream_t stream) {
    const float* x      = (const float*)d_in[0];
    const float* offset = (const float*)d_in[1];
    const float* mask   = (const float*)d_in[2];
    const float* weight = (const float*)d_in[3];
    const float* bias   = (const float*)d_in[4];
    float* out = (float*)d_out;
    char* ws = (char*)d_ws;
    unsigned short* xt  = (unsigned short*)ws;                        // 8 MB
    unsigned short* wtf = (unsigned short*)(ws + 8388608);            // 72 KB
    float* wfix         = (float*)(ws + 8388608 + 73728);             // 144 KB
    unsigned* counter   = (unsigned*)(ws + 8388608 + 73728 + 147456);
    unsigned* flags     = counter + 32;                               // 64 KB

    hipMemsetAsync(counter, 0, 4, stream);
    k_transpose<<<B_ * H_, 256, 0, stream>>>(x, xt);
    k_weight<<<144, 256, 0, stream>>>(weight, wtf);
    k_wfix<<<144, 256, 0, stream>>>(weight, wfix);
    k_main<<<NBLK, 512, 0, stream>>>(xt, offset, mask, wtf, bias, out, counter, flags);
    k_fixup<<<256, 256, 0, stream>>>(xt, offset, mask, wfix, counter, flags, out);
}

// Round 11
// 72.285 us; speedup vs baseline: 1.2944x; 1.0317x over previous
//
#include <hip/hip_runtime.h>

#define B_   4
#define CIN  64
#define COUT 64
#define H_   128
#define W_   128
#define HW   (H_*W_)
#define KK   9
#define HALO 3
#define TI   4
#define TJ   16
#define ROWS_R (TI + 2*HALO)            // 10
#define COLS_R (TJ + 2*HALO)            // 22
#define RECS   (ROWS_R * COLS_R)        // 220
#define OFFB   (RECS * 128)             // 28160
#define SMEMB  (OFFB + 27 * TI * TJ * 4) // 35072
#define NBLK   1024                     // 4 b x 32 ti x 8 tj

typedef short bf16x8 __attribute__((ext_vector_type(8)));
typedef float f32x4  __attribute__((ext_vector_type(4)));
typedef float f32x2  __attribute__((ext_vector_type(2)));
typedef unsigned int u32;
typedef unsigned int u32x4 __attribute__((ext_vector_type(4)));

__device__ __forceinline__ unsigned short f2bf(float f) {
    unsigned int u = __float_as_uint(f);
    u = (u + 0x7FFFu + ((u >> 16) & 1u)) >> 16;
    return (unsigned short)u;
}

// ---- Kernel 1: x (B,CIN,H,W) f32 -> xt (B,H,W,CIN) bf16 ----
__global__ __launch_bounds__(256) void k_transpose(const float* __restrict__ x,
                                                   unsigned short* __restrict__ xt) {
    __shared__ float lds[64 * 129];
    int bi = blockIdx.x;
    int b = bi >> 7, i = bi & 127;
    int tid = threadIdx.x;
#pragma unroll
    for (int cc = 0; cc < 32; ++cc) {
        int c = cc * 2 + (tid >> 7);
        int w = tid & 127;
        lds[c * 129 + w] = x[((b * CIN + c) * H_ + i) * W_ + w];
    }
    __syncthreads();
#pragma unroll
    for (int q = 0; q < 32; ++q) {
        int c = tid & 63;
        int w = q * 4 + (tid >> 6);
        xt[((b * H_ + i) * W_ + w) * CIN + c] = f2bf(lds[c * 129 + w]);
    }
}

// ---- Kernel 2: weight -> MFMA B-fragment order (bf16) ----
__global__ __launch_bounds__(256) void k_weight(const float* __restrict__ w,
                                                unsigned short* __restrict__ wtf) {
    int t = blockIdx.x * 256 + threadIdx.x;
    if (t >= 18 * 4 * 64 * 8) return;
    int j    = t & 7;
    int lane = (t >> 3) & 63;
    int nt   = (t >> 9) & 3;
    int s    = t >> 11;
    int kg   = s * 32 + ((lane >> 4) << 3) + j;
    int n    = nt * 16 + (lane & 15);
    int kpos = kg >> 6, c = kg & 63;
    wtf[t] = f2bf(w[(n * CIN + c) * 9 + kpos]);
}

// ---- Main: 4x16 tile, 8 waves = 4 rows x 2 K-halves.
//      Phase 1: gather+blend 9 A-frags into registers.
//      Phase 2: pure B-load + MFMA loop. sched_barrier between. ----
__global__ __launch_bounds__(512, 4) void k_main(
    const unsigned short* __restrict__ xt,
    const float* __restrict__ offset,
    const float* __restrict__ mask,
    const unsigned short* __restrict__ wtf,
    const float* __restrict__ bias,
    float* __restrict__ out) {
    __shared__ __align__(16) unsigned char smem[SMEMB];   // 34.25 KB

    const int tid  = threadIdx.x;
    const int lane = tid & 63;
    const int wv   = tid >> 6;          // 0..7
    const int wvl  = wv & 3;            // px row within tile
    const int half = wv >> 2;           // K-half
    // XCD swizzle (1024 % 8 == 0)
    const int T  = ((blockIdx.x & 7) << 7) + (blockIdx.x >> 3);
    const int b  = T >> 8;
    const int i0 = ((T >> 3) & 31) * TI;
    const int j0 = (T & 7) * TJ;
    const char* xb = (const char*)xt + (size_t)b * HW * 128;

    // -------- stage 10x22 record region, chunk-rotation swizzle --------
    {
        const int iA = i0 - HALO, jA = j0 - HALO;
#pragma unroll
        for (int k = 0; k < 4; ++k) {
            int idx = k * 512 + tid;          // 1760 chunks
            if (idx < RECS * 8) {
                int rec = idx >> 3, c = idx & 7;
                int rr = rec / COLS_R, cc = rec - rr * COLS_R;
                int gr = min(max(iA + rr, 0), H_ - 1);
                int gc = min(max(jA + cc, 0), W_ - 1);
                u32x4 v = *(const u32x4*)(xb + (((gr << 7) + gc) << 7) + (c << 4));
                *(u32x4*)(smem + (rec << 7) + (((c + rec) & 7) << 4)) = v;
            }
        }
    }
    // -------- stage offset+mask planes [27][4][16] f32 --------
    {
        const float* op = offset + (size_t)b * 18 * HW;
        const float* mp = mask   + (size_t)b * 9  * HW;
        if (tid < 432) {
            int q = tid >> 4, rem = tid & 15;
            int row = rem >> 2, c4 = (rem & 3) << 2;
            const float* src = (q < 18 ? op + q * HW : mp + (q - 18) * HW)
                               + (i0 + row) * W_ + j0 + c4;
            *(f32x4*)(smem + OFFB + tid * 16) = *(const f32x4*)src;
        }
    }
    __syncthreads();

    const int p  = lane & 15;            // px col
    const int g  = lane >> 4;            // channel group
    const int ir = i0 + wvl;
    const int jc = j0 + p;
    const float* offl = (const float*)(smem + OFFB) + wvl * 16 + p;
    const bf16x8* wp = (const bf16x8*)wtf;
    f32x4 acc0 = {0,0,0,0}, acc1 = {0,0,0,0}, acc2 = {0,0,0,0}, acc3 = {0,0,0,0};
    bf16x8 pa0, pa1, pa2, pa3, pa4, pa5, pa6, pa7, pa8;

    // one h-step: gather 4 corners (LDS, rare global fallback) + blend -> PA
#define KP_HSTEP(H, PA) do { \
    int ch = (H) * 4 + g; \
    u32x4 q00 = *(const u32x4*)(smem + (r00 << 7) + (((ch + r00) & 7) << 4)); \
    u32x4 q01 = *(const u32x4*)(smem + (r01 << 7) + (((ch + r01) & 7) << 4)); \
    u32x4 q10 = *(const u32x4*)(smem + (r10 << 7) + (((ch + r10) & 7) << 4)); \
    u32x4 q11 = *(const u32x4*)(smem + (r11 << 7) + (((ch + r11) & 7) << 4)); \
    if (!inr) { \
        int c = (g << 4) + ((H) << 6); \
        q00 = *(const u32x4*)(xb + a00 + c); \
        q01 = *(const u32x4*)(xb + a01 + c); \
        q10 = *(const u32x4*)(xb + a10 + c); \
        q11 = *(const u32x4*)(xb + a11 + c); \
    } \
    u32x4 po; \
    _Pragma("unroll") \
    for (int q = 0; q < 4; ++q) { \
        f32x2 c00 = {__uint_as_float(q00[q] << 16), __uint_as_float(q00[q] & 0xFFFF0000u)}; \
        f32x2 c01 = {__uint_as_float(q01[q] << 16), __uint_as_float(q01[q] & 0xFFFF0000u)}; \
        f32x2 c10 = {__uint_as_float(q10[q] << 16), __uint_as_float(q10[q] & 0xFFFF0000u)}; \
        f32x2 c11 = {__uint_as_float(q11[q] << 16), __uint_as_float(q11[q] & 0xFFFF0000u)}; \
        f32x2 r = wx * c00 + wy * c01 + wz * c10 + ww * c11; \
        po[q] = __builtin_amdgcn_perm(__float_as_uint(r.y) + 0x8000u, \
                                      __float_as_uint(r.x) + 0x8000u, 0x07060302u); \
    } \
    *(u32x4*)&(PA) = po; } while (0)

#define KP_META(KP) \
    float oi  = offl[(2*(KP)) * 64]; \
    float oj  = offl[(2*(KP)+1) * 64]; \
    float msk = offl[(18+(KP)) * 64]; \
    float ci = oi + (float)(ir + (KP)/3 - 1); \
    float cj = oj + (float)(jc + (KP)%3 - 1); \
    float fli = floorf(ci), flj = floorf(cj); \
    float fi = ci - fli, fj = cj - flj; \
    int li = (int)fli, lj = (int)flj; \
    int rli = li - (i0 - HALO), rlj = lj - (j0 - HALO); \
    bool inr = ((unsigned)rli <= (unsigned)(ROWS_R-2)) && \
               ((unsigned)rlj <= (unsigned)(COLS_R-2)); \
    float vy0 = (li   >= 0 && li   < H_) ? 1.f : 0.f; \
    float vy1 = (li+1 >= 0 && li+1 < H_) ? 1.f : 0.f; \
    float vx0 = (lj   >= 0 && lj   < W_) ? 1.f : 0.f; \
    float vx1 = (lj+1 >= 0 && lj+1 < W_) ? 1.f : 0.f; \
    float gi = fi * msk, gj = fj * msk; \
    float w11 = gi * fj; \
    float w4x = (msk - gi - gj + w11) * vy0 * vx0; \
    float w4y = (gj - w11) * vy0 * vx1; \
    float w4z = (gi - w11) * vy1 * vx0; \
    float w4w = w11 * vy1 * vx1; \
    f32x2 wx = {w4x, w4x}, wy = {w4y, w4y}, wz = {w4z, w4z}, ww = {w4w, w4w}; \
    int y0 = min(max(li,   0), H_-1), y1 = min(max(li+1, 0), H_-1); \
    int x0 = min(max(lj,   0), W_-1), x1 = min(max(lj+1, 0), W_-1); \
    int a00 = ((y0 << 7) + x0) << 7, a01 = ((y0 << 7) + x1) << 7; \
    int a10 = ((y1 << 7) + x0) << 7, a11 = ((y1 << 7) + x1) << 7; \
    int rli_c = min(max(rli, 0), ROWS_R-2), rlj_c = min(max(rlj, 0), COLS_R-2); \
    int r00 = rli_c * COLS_R + rlj_c; \
    int r01 = r00 + 1, r10 = r00 + COLS_R, r11 = r00 + COLS_R + 1;

#define KP_FULL(KP, PA, PB) do { KP_META(KP); KP_HSTEP(0, PA); KP_HSTEP(1, PB); } while (0)
#define KP_ONE(KP, H, PA)   do { KP_META(KP); KP_HSTEP(H, PA); } while (0)

    // -------- phase 1: all gathers + blends into pa0..pa8 --------
    if (!half) {
        KP_FULL(0, pa0, pa1); KP_FULL(1, pa2, pa3); KP_FULL(2, pa4, pa5);
        KP_FULL(3, pa6, pa7); KP_ONE(8, 0, pa8);
    } else {
        KP_FULL(4, pa0, pa1); KP_FULL(5, pa2, pa3); KP_FULL(6, pa4, pa5);
        KP_FULL(7, pa6, pa7); KP_ONE(8, 1, pa8);
    }

    __builtin_amdgcn_sched_barrier(0);   // keep phase 2 strictly after phase 1

    // -------- phase 2: pure B-load + MFMA --------
#define MM(PA, S) do { \
    acc0 = __builtin_amdgcn_mfma_f32_16x16x32_bf16(PA, wp[((S)*4+0)*64 + lane], acc0, 0, 0, 0); \
    acc1 = __builtin_amdgcn_mfma_f32_16x16x32_bf16(PA, wp[((S)*4+1)*64 + lane], acc1, 0, 0, 0); \
    acc2 = __builtin_amdgcn_mfma_f32_16x16x32_bf16(PA, wp[((S)*4+2)*64 + lane], acc2, 0, 0, 0); \
    acc3 = __builtin_amdgcn_mfma_f32_16x16x32_bf16(PA, wp[((S)*4+3)*64 + lane], acc3, 0, 0, 0); } while (0)

    if (!half) {
        MM(pa0, 0); MM(pa1, 1); MM(pa2, 2); MM(pa3, 3);
        MM(pa4, 4); MM(pa5, 5); MM(pa6, 6); MM(pa7, 7); MM(pa8, 16);
    } else {
        MM(pa0, 8);  MM(pa1, 9);  MM(pa2, 10); MM(pa3, 11);
        MM(pa4, 12); MM(pa5, 13); MM(pa6, 14); MM(pa7, 15); MM(pa8, 17);
    }

    // -------- epilogue: K-reduce via LDS, bias, coalesced write --------
    __syncthreads();
    f32x4* dump = (f32x4*)smem;                  // [nt][4 rows][64 lanes]
    if (half) {
        dump[(0*4 + wvl)*64 + lane] = acc0;
        dump[(1*4 + wvl)*64 + lane] = acc1;
        dump[(2*4 + wvl)*64 + lane] = acc2;
        dump[(3*4 + wvl)*64 + lane] = acc3;
    }
    __syncthreads();
    if (!half) {
        acc0 += dump[(0*4 + wvl)*64 + lane];
        acc1 += dump[(1*4 + wvl)*64 + lane];
        acc2 += dump[(2*4 + wvl)*64 + lane];
        acc3 += dump[(3*4 + wvl)*64 + lane];
        float bs0 = bias[p], bs1 = bias[16 + p], bs2 = bias[32 + p], bs3 = bias[48 + p];
#pragma unroll
        for (int r = 0; r < 4; ++r) { acc0[r] += bs0; acc1[r] += bs1; acc2[r] += bs2; acc3[r] += bs3; }
    }
    __syncthreads();
    float* cst = (float*)smem;                   // [64 cout][68 px]
    if (!half) {
        const int pm = wvl * 16 + (g << 2);      // px-local base
        *(f32x4*)&cst[(p)      * 68 + pm] = acc0;
        *(f32x4*)&cst[(16 + p) * 68 + pm] = acc1;
        *(f32x4*)&cst[(32 + p) * 68 + pm] = acc2;
        *(f32x4*)&cst[(48 + p) * 68 + pm] = acc3;
    }
    __syncthreads();
    const size_t obase = (size_t)b * (COUT * HW) + i0 * W_ + j0;
#pragma unroll
    for (int k = 0; k < 2; ++k) {
        int idx = k * 512 + tid;                 // 1024 f32x4 chunks
        int cout = idx >> 4, chunk = idx & 15;
        int row = chunk >> 2, cq = (chunk & 3) << 2;
        f32x4 vv = *(const f32x4*)&cst[cout * 68 + chunk * 4];
        __builtin_nontemporal_store(vv,
            (f32x4*)&out[obase + (size_t)cout * HW + row * W_ + cq]);
    }
}

extern "C" void kernel_launch(void* const* d_in, const int* in_sizes, int n_in,
                              void* d_out, int out_size, void* d_ws, size_t ws_size,
                              hipStream_t stream) {
    const float* x      = (const float*)d_in[0];
    const float* offset = (const float*)d_in[1];
    const float* mask   = (const float*)d_in[2];
    const float* weight = (const float*)d_in[3];
    const float* bias   = (const float*)d_in[4];
    float* out = (float*)d_out;
    char* ws = (char*)d_ws;
    unsigned short* xt  = (unsigned short*)ws;                        // 8 MB
    unsigned short* wtf = (unsigned short*)(ws + 8388608);            // 72 KB

    k_transpose<<<B_ * H_, 256, 0, stream>>>(x, xt);
    k_weight<<<144, 256, 0, stream>>>(weight, wtf);
    k_main<<<NBLK, 512, 0, stream>>>(xt, offset, mask, wtf, bias, out);
}